// Round 8
// baseline (43.660 us; speedup 1.0000x reference)
//
#include <hip/hip_runtime.h>

#define Cc 8
#define Hh 128
#define Ww 128
#define Nn 64
#define Bb 8
#define Dd 169            // (C+2)*C + C + C*C + C + C + 1
#define HW (Hh * Ww)
#define CHUNKS 4          // blocks per (b,n)
#define NBLK (Bb * Nn * CHUNKS)   // 2048
#define PXB (HW / CHUNKS)         // 4096 px per block
#define GROUPS 4                  // 4 float4-groups -> 16 px per thread

#define INV128 (1.0f / 128.0f)

typedef __fp16 f16x2 __attribute__((ext_vector_type(2)));

static __device__ __forceinline__ f16x2 pk(float a, float b) {
    return __builtin_amdgcn_cvt_pkrtz(a, b);   // v_cvt_pkrtz_f16_f32
}
static __device__ __forceinline__ uint32_t pku(float a, float b) {
    f16x2 t = pk(a, b); uint32_t u; __builtin_memcpy(&u, &t, 4); return u;
}
static __device__ __forceinline__ f16x2 u2h(uint32_t u) {
    f16x2 r; __builtin_memcpy(&r, &u, 4); return r;
}
static __device__ __forceinline__ uint32_t rfl(uint32_t x) {
    return __builtin_amdgcn_readfirstlane(x);  // -> SGPR (block-uniform)
}

#if __has_builtin(__builtin_amdgcn_fdot2)
static __device__ __forceinline__ float dot2(uint32_t w, f16x2 f, float acc) {
    return __builtin_amdgcn_fdot2(u2h(w), f, acc, false);   // v_dot2_f32_f16: 2 MAC/instr
}
#else
static __device__ __forceinline__ float dot2(uint32_t w, f16x2 f, float acc) {
    f16x2 wv = u2h(w);   // lowers to v_fma_mix on gfx9: 1 MAC/instr fallback
    return acc + (float)wv.x * (float)f.x + (float)wv.y * (float)f.y;
}
#endif

static __device__ __forceinline__ float pick(float4 v, int j) {
    return j == 0 ? v.x : j == 1 ? v.y : j == 2 ? v.z : v.w;
}

__global__ __launch_bounds__(256)
void seg_dice_main(const float* __restrict__ seg_feat,
                   const float* __restrict__ conv_weight,
                   const float* __restrict__ mask,
                   const int*   __restrict__ ind,
                   const float* __restrict__ target,
                   float* __restrict__ ws) {
    // XCD-chunked id: the 4 chunks of one bn land on the same XCD (gather L2 reuse)
    const int g     = (blockIdx.x & 7) * (NBLK / 8) + (blockIdx.x >> 3);
    const int bn    = g >> 2;
    const int chunk = g & (CHUNKS - 1);
    const int b     = bn >> 6;
    const int tid   = threadIdx.x;

    __shared__ float w_s[Dd];
    const int ind_bn = ind[bn];

    // gather weight vector: conv_weight[b, d, ind]
    for (int i = tid; i < Dd; i += 256)
        w_s[i] = conv_weight[(size_t)b * Dd * HW + (size_t)i * HW + ind_bn];
    __syncthreads();

    // ---- pack weights as f16 pairs (c-dim in halves), force into SGPRs ----
    uint32_t pw1[40];   // layer1: o-row = pairs 5o..5o+4; pair 5o+4 = (w8,w9)
    #pragma unroll
    for (int j = 0; j < 40; ++j) pw1[j] = rfl(pku(w_s[2 * j], w_s[2 * j + 1]));
    uint32_t pw2[32];   // layer2: o-row = pairs 4o..4o+3
    #pragma unroll
    for (int j = 0; j < 32; ++j) pw2[j] = rfl(pku(w_s[88 + 2 * j], w_s[89 + 2 * j]));
    uint32_t pw3[4];    // layer3
    #pragma unroll
    for (int j = 0; j < 4; ++j)  pw3[j] = rfl(pku(w_s[160 + 2 * j], w_s[161 + 2 * j]));
    // biases as uniform f32 (VGPR; dot2's src2 must be VGPR since src0 is the SGPR)
    float b1f[8], b2f[8];
    #pragma unroll
    for (int o = 0; o < 8; ++o) { b1f[o] = w_s[80 + o]; b2f[o] = w_s[152 + o]; }
    const float b3f = w_s[168];

    const float m  = mask[bn];
    const float x0 = (float)(ind_bn & (Ww - 1));
    const float y0 = (float)(ind_bn >> 7);

    const float* seg_b  = seg_feat + (size_t)b * Cc * HW;
    const float* tgt_bn = target   + (size_t)bn * HW;

    float inter = 0.f, ps = 0.f, ts = 0.f;
    const int pbase = chunk * PXB + (tid << 2);

    #pragma unroll 1
    for (int it = 0; it < GROUPS; ++it) {
        const int p = pbase + (it << 10);

        const float4 t4 = *(const float4*)(tgt_bn + p);
        float4 f4[8];
        #pragma unroll
        for (int c = 0; c < 8; ++c) f4[c] = *(const float4*)(seg_b + c * HW + p);

        const float yrf = ((float)(p >> 7)        - y0) * INV128;
        const float xbf = ((float)(p & (Ww - 1)) - x0) * INV128;

        #pragma unroll
        for (int j = 0; j < 4; ++j) {
            // feature pairs: (c0,c1),(c2,c3),(c4,c5),(c6,c7),(xr,yr)
            const f16x2 fp0 = pk(pick(f4[0], j), pick(f4[1], j));
            const f16x2 fp1 = pk(pick(f4[2], j), pick(f4[3], j));
            const f16x2 fp2 = pk(pick(f4[4], j), pick(f4[5], j));
            const f16x2 fp3 = pk(pick(f4[6], j), pick(f4[7], j));
            const f16x2 fpx = pk(xbf + (float)j * INV128, yrf);

            // ---- layer 1: 10 -> 8, relu (f32 accum) ----
            float h1[8];
            #pragma unroll
            for (int o = 0; o < 8; ++o) {
                float a = b1f[o];
                a = dot2(pw1[5 * o + 0], fp0, a);
                a = dot2(pw1[5 * o + 1], fp1, a);
                a = dot2(pw1[5 * o + 2], fp2, a);
                a = dot2(pw1[5 * o + 3], fp3, a);
                a = dot2(pw1[5 * o + 4], fpx, a);
                h1[o] = fmaxf(a, 0.f);
            }
            const f16x2 hp0 = pk(h1[0], h1[1]);
            const f16x2 hp1 = pk(h1[2], h1[3]);
            const f16x2 hp2 = pk(h1[4], h1[5]);
            const f16x2 hp3 = pk(h1[6], h1[7]);

            // ---- layer 2: 8 -> 8, relu ----
            float h2[8];
            #pragma unroll
            for (int o = 0; o < 8; ++o) {
                float a = b2f[o];
                a = dot2(pw2[4 * o + 0], hp0, a);
                a = dot2(pw2[4 * o + 1], hp1, a);
                a = dot2(pw2[4 * o + 2], hp2, a);
                a = dot2(pw2[4 * o + 3], hp3, a);
                h2[o] = fmaxf(a, 0.f);
            }
            const f16x2 gp0 = pk(h2[0], h2[1]);
            const f16x2 gp1 = pk(h2[2], h2[3]);
            const f16x2 gp2 = pk(h2[4], h2[5]);
            const f16x2 gp3 = pk(h2[6], h2[7]);

            // ---- layer 3: 8 -> 1, sigmoid + dice (f32) ----
            float z = b3f;
            z = dot2(pw3[0], gp0, z);
            z = dot2(pw3[1], gp1, z);
            z = dot2(pw3[2], gp2, z);
            z = dot2(pw3[3], gp3, z);

            const float o_ = __builtin_amdgcn_rcpf(1.f + __expf(-z));
            const float tv = pick(t4, j);
            inter = fmaf(o_, tv, inter);
            ps    = fmaf(o_, o_, ps);
            ts    = fmaf(tv, tv, ts);
        }
    }

    const float m2 = m * m;
    inter *= m2; ps *= m2; ts *= m2;

    // wave reduce then cross-wave via LDS
    #pragma unroll
    for (int off = 32; off > 0; off >>= 1) {
        inter += __shfl_down(inter, off);
        ps    += __shfl_down(ps,    off);
        ts    += __shfl_down(ts,    off);
    }
    __shared__ float red[3][4];
    const int wave = tid >> 6;
    if ((tid & 63) == 0) { red[0][wave] = inter; red[1][wave] = ps; red[2][wave] = ts; }
    __syncthreads();
    if (tid == 0) {
        const int local = (bn & 63) * CHUNKS + chunk;   // 0..255 within batch b
        ws[(b * 3 + 0) * 256 + local] = red[0][0] + red[0][1] + red[0][2] + red[0][3];
        ws[(b * 3 + 1) * 256 + local] = red[1][0] + red[1][1] + red[1][2] + red[1][3];
        ws[(b * 3 + 2) * 256 + local] = red[2][0] + red[2][1] + red[2][2] + red[2][3];
    }
}

// deterministic epilogue: 24 series (8 b x 3 comps) x 256 partials
__global__ void seg_dice_final(const float* __restrict__ ws, float* __restrict__ out) {
    __shared__ float red[24][4];
    const int tid = threadIdx.x;  // 128 threads
    if (tid < 96) {
        const int series = tid >> 2;   // 0..23
        const int part   = tid & 3;    // 0..3
        const float4* p = (const float4*)(ws + series * 256 + part * 64);
        float s = 0.f;
        #pragma unroll
        for (int i = 0; i < 16; ++i) { const float4 v = p[i]; s += (v.x + v.y) + (v.z + v.w); }
        red[series][part] = s;
    }
    __syncthreads();
    if (tid == 0) {
        float acc = 0.f;
        #pragma unroll
        for (int b = 0; b < Bb; ++b) {
            const float inter = red[b*3+0][0] + red[b*3+0][1] + red[b*3+0][2] + red[b*3+0][3];
            const float p2    = red[b*3+1][0] + red[b*3+1][1] + red[b*3+1][2] + red[b*3+1][3];
            const float t2    = red[b*3+2][0] + red[b*3+2][1] + red[b*3+2][2] + red[b*3+2][3];
            acc += 1.0f - (2.0f * inter + 1.0f) / (p2 + t2 + 1.0f);
        }
        out[0] = acc * (1.0f / (float)Bb);
    }
}

extern "C" void kernel_launch(void* const* d_in, const int* in_sizes, int n_in,
                              void* d_out, int out_size, void* d_ws, size_t ws_size,
                              hipStream_t stream) {
    const float* seg_feat    = (const float*)d_in[0];
    const float* conv_weight = (const float*)d_in[1];
    const float* mask        = (const float*)d_in[2];
    const int*   ind         = (const int*)d_in[3];
    const float* target      = (const float*)d_in[4];
    float* out = (float*)d_out;
    float* ws  = (float*)d_ws;

    seg_dice_main<<<NBLK, 256, 0, stream>>>(seg_feat, conv_weight, mask, ind, target, ws);
    seg_dice_final<<<1, 128, 0, stream>>>(ws, out);
}